// Round 2
// baseline (849.198 us; speedup 1.0000x reference)
//
#include <hip/hip_runtime.h>
#include <math.h>

#define UNITS 1024
#define EMBD  256
#define BATCH 64
#define TLEN  128
#define VOCAB 32000
#define GIN_D (UNITS + EMBD)   // 1280

typedef short short8 __attribute__((ext_vector_type(8)));
typedef float f32x4  __attribute__((ext_vector_type(4)));

__device__ __forceinline__ unsigned short f2bf(float f) {
    unsigned int u = __float_as_uint(f);
    u += 0x7fffu + ((u >> 16) & 1u);   // RNE
    return (unsigned short)(u >> 16);
}
__device__ __forceinline__ unsigned int packbf(float lo, float hi) {
    return (unsigned int)f2bf(lo) | ((unsigned int)f2bf(hi) << 16);
}

// ---------------- K1: c[b,j] = hidden[b,:] @ W2[:,j] + b1[j] + b2[j] ----------------
__global__ __launch_bounds__(256) void k_c(const float* __restrict__ hidden,
                                           const float* __restrict__ W2,
                                           const float* __restrict__ b1,
                                           const float* __restrict__ b2,
                                           float* __restrict__ c) {
    const int lane = threadIdx.x & 63;
    const int j = blockIdx.x * 64 + lane;
    const int b = blockIdx.y * 4 + (threadIdx.x >> 6);
    const float* hrow = hidden + (size_t)b * UNITS;
    const float* wcol = W2 + j;
    float acc = 0.f;
#pragma unroll 8
    for (int k = 0; k < UNITS; ++k)
        acc = fmaf(hrow[k], wcol[(size_t)k * UNITS], acc);
    c[(size_t)b * UNITS + j] = acc + b1[j] + b2[j];
}

// ---------------- K2: score via bf16 MFMA -------------------------------------------
// score[b,t] = sum_j tanh((enc@W1)[b,t,j] + c[b,j]) * V[j]
// 128(t) x 128(j) tile per block, K=1024 in BK=64 chunks, fp32->bf16 cvt fused
// into LDS staging. As: [t][k] (enc natural), Bs: [j][k] (W1 transposed in LDS).
// Row stride 72 bf16 (144 B): frag b128 reads land 2-way/bank (free).
__global__ __launch_bounds__(256, 2) void k_score(const float* __restrict__ enc,
                                                  const float* __restrict__ W1,
                                                  const float* __restrict__ c,
                                                  const float* __restrict__ V,
                                                  float* __restrict__ score) {
    __shared__ unsigned short As[128 * 72];
    __shared__ unsigned short Bs[128 * 72];
    const int jt   = blockIdx.x;         // 0..7
    const int b    = blockIdx.y;         // 0..63
    const int tid  = threadIdx.x;
    const int lane = tid & 63;
    const int wid  = tid >> 6;           // 0..3
    const int wr   = wid & 1;            // wave row-block (64 t)
    const int wc   = wid >> 1;           // wave col-block (64 j)
    const int quad = lane >> 4;          // 0..3
    const int l16  = lane & 15;

    const float* encb = enc + (size_t)b * TLEN * UNITS;
    const float* w1b  = W1 + jt * 128;

    f32x4 acc[4][4];
#pragma unroll
    for (int i = 0; i < 4; ++i)
#pragma unroll
        for (int j = 0; j < 4; ++j)
            acc[i][j] = (f32x4){0.f, 0.f, 0.f, 0.f};

    const int ar = tid >> 4;   // 0..15  A row base
    const int ac = tid & 15;   // A float4-col (k/4)
    const int bp = tid >> 5;   // 0..7   B k-pair base
    const int bj = tid & 31;   // B float4-col (j/4)

    for (int kc = 0; kc < UNITS; kc += 64) {
        float4 av[8];
#pragma unroll
        for (int rr = 0; rr < 8; ++rr)
            av[rr] = *(const float4*)(encb + (size_t)(ar + rr * 16) * UNITS + kc + ac * 4);
        float4 bv0[4], bv1[4];
#pragma unroll
        for (int kk = 0; kk < 4; ++kk) {
            const int k0 = 2 * (bp + 8 * kk);
            bv0[kk] = *(const float4*)(w1b + (size_t)(kc + k0) * UNITS + bj * 4);
            bv1[kk] = *(const float4*)(w1b + (size_t)(kc + k0 + 1) * UNITS + bj * 4);
        }
        __syncthreads();
#pragma unroll
        for (int rr = 0; rr < 8; ++rr) {
            ushort4 h;
            h.x = f2bf(av[rr].x); h.y = f2bf(av[rr].y);
            h.z = f2bf(av[rr].z); h.w = f2bf(av[rr].w);
            *(ushort4*)&As[(ar + rr * 16) * 72 + ac * 4] = h;
        }
#pragma unroll
        for (int kk = 0; kk < 4; ++kk) {
            const int k0 = 2 * (bp + 8 * kk);
            *(unsigned int*)&Bs[(bj * 4 + 0) * 72 + k0] = packbf(bv0[kk].x, bv1[kk].x);
            *(unsigned int*)&Bs[(bj * 4 + 1) * 72 + k0] = packbf(bv0[kk].y, bv1[kk].y);
            *(unsigned int*)&Bs[(bj * 4 + 2) * 72 + k0] = packbf(bv0[kk].z, bv1[kk].z);
            *(unsigned int*)&Bs[(bj * 4 + 3) * 72 + k0] = packbf(bv0[kk].w, bv1[kk].w);
        }
        __syncthreads();
#pragma unroll
        for (int kk = 0; kk < 2; ++kk) {
            const int kb = kk * 32 + quad * 8;
            short8 af[4], bfr[4];
#pragma unroll
            for (int mt = 0; mt < 4; ++mt)
                af[mt] = *(const short8*)&As[(wr * 64 + mt * 16 + l16) * 72 + kb];
#pragma unroll
            for (int nt = 0; nt < 4; ++nt)
                bfr[nt] = *(const short8*)&Bs[(wc * 64 + nt * 16 + l16) * 72 + kb];
#pragma unroll
            for (int mt = 0; mt < 4; ++mt)
#pragma unroll
                for (int nt = 0; nt < 4; ++nt)
                    acc[mt][nt] = __builtin_amdgcn_mfma_f32_16x16x32_bf16(
                        af[mt], bfr[nt], acc[mt][nt], 0, 0, 0);
        }
    }

    // epilogue: per-lane cols = jt*128 + wc*64 + nt*16 + l16; rows = wr*64 + mt*16 + quad*4 + reg
    float cv[4], vv[4];
#pragma unroll
    for (int nt = 0; nt < 4; ++nt) {
        const int col = wc * 64 + nt * 16 + l16;
        cv[nt] = c[(size_t)b * UNITS + jt * 128 + col];
        vv[nt] = V[jt * 128 + col];
    }
    float rs[16];
#pragma unroll
    for (int mt = 0; mt < 4; ++mt)
#pragma unroll
        for (int reg = 0; reg < 4; ++reg) {
            float s = 0.f;
#pragma unroll
            for (int nt = 0; nt < 4; ++nt)
                s += tanhf(acc[mt][nt][reg] + cv[nt]) * vv[nt];
            rs[mt * 4 + reg] = s;
        }
#pragma unroll
    for (int off = 1; off < 16; off <<= 1)
#pragma unroll
        for (int i = 0; i < 16; ++i)
            rs[i] += __shfl_xor(rs[i], off);
    if (l16 == 0) {
#pragma unroll
        for (int mt = 0; mt < 4; ++mt)
#pragma unroll
            for (int reg = 0; reg < 4; ++reg)
                atomicAdd(&score[b * TLEN + wr * 64 + mt * 16 + quad * 4 + reg],
                          rs[mt * 4 + reg]);
    }
}

// ---------------- K3: softmax over t (bV is softmax-invariant -> skipped) -----------
__global__ void k_softmax(const float* __restrict__ score, float* __restrict__ attw) {
    const int b = blockIdx.x;
    const int lane = threadIdx.x;  // 0..63
    float s0 = score[b * TLEN + lane];
    float s1 = score[b * TLEN + 64 + lane];
    float m = fmaxf(s0, s1);
#pragma unroll
    for (int off = 1; off < 64; off <<= 1) m = fmaxf(m, __shfl_xor(m, off));
    const float e0 = expf(s0 - m);
    const float e1 = expf(s1 - m);
    float s = e0 + e1;
#pragma unroll
    for (int off = 1; off < 64; off <<= 1) s += __shfl_xor(s, off);
    const float inv = 1.f / s;
    attw[b * TLEN + lane] = e0 * inv;
    attw[b * TLEN + 64 + lane] = e1 * inv;
}

// ---------------- K4: context[b,k] = sum_t attw[b,t] * enc[b,t,k] -> gin[:, :1024] --
__global__ __launch_bounds__(256) void k_context(const float* __restrict__ enc,
                                                 const float* __restrict__ attw,
                                                 float* __restrict__ gin) {
    const int b = blockIdx.y;
    const int k = blockIdx.x * 256 + threadIdx.x;
    __shared__ float w[TLEN];
    if (threadIdx.x < TLEN) w[threadIdx.x] = attw[b * TLEN + threadIdx.x];
    __syncthreads();
    const float* e = enc + (size_t)b * TLEN * UNITS + k;
    float acc = 0.f;
#pragma unroll 8
    for (int t = 0; t < TLEN; ++t)
        acc = fmaf(w[t], e[(size_t)t * UNITS], acc);
    gin[(size_t)b * GIN_D + k] = acc;
}

// ---------------- K5: embedding gather -> gin[:, 1024:1280] -------------------------
__global__ void k_embed(const int* __restrict__ x, const float* __restrict__ emb,
                        float* __restrict__ gin) {
    const int b = blockIdx.x;
    const int e = threadIdx.x;  // 0..255
    const int row = x[b];
    gin[(size_t)b * GIN_D + UNITS + e] = emb[(size_t)row * EMBD + e];
}

// ---------------- K6: GRU gates + state. h0==0 => gates_h==0, r dead. ---------------
__global__ __launch_bounds__(256) void k_gru(const float* __restrict__ gin,
                                             const float* __restrict__ gru_k,
                                             const float* __restrict__ gru_b,
                                             float* __restrict__ state,
                                             float* __restrict__ stateT) {
    const int lane = threadIdx.x & 63;
    const int i = blockIdx.x * 64 + lane;
    const int b = blockIdx.y * 4 + (threadIdx.x >> 6);
    const float* g = gin + (size_t)b * GIN_D;
    const float* wz = gru_k + i;
    const float* wh = gru_k + 2048 + i;
    float az = 0.f, ah = 0.f;
#pragma unroll 4
    for (int k = 0; k < GIN_D; ++k) {
        const float gv = g[k];
        az = fmaf(gv, wz[(size_t)k * 3072], az);
        ah = fmaf(gv, wh[(size_t)k * 3072], ah);
    }
    az += gru_b[i];
    ah += gru_b[2048 + i];
    const float z = 1.f / (1.f + expf(-az));
    const float hh = tanhf(ah);
    const float st = (1.f - z) * hh;
    state[(size_t)b * UNITS + i] = st;
    stateT[(size_t)i * BATCH + b] = st;
}

// ---------------- K7: logits = state @ fc_W + fc_b (no k-split, no atomics) ---------
__global__ __launch_bounds__(256) void k_fc(const float* __restrict__ stateT,
                                            const float* __restrict__ fc_W,
                                            const float* __restrict__ fc_b,
                                            float* __restrict__ logits) {
    const int lane = threadIdx.x & 63;
    const int col = blockIdx.x * 64 + lane;
    const int b0 = (int)(threadIdx.x >> 6) * 16;
    float acc[16];
#pragma unroll
    for (int i = 0; i < 16; ++i) acc[i] = 0.f;
    const float* wp = fc_W + col;
    const float* sp = stateT + b0;
#pragma unroll 2
    for (int k = 0; k < UNITS; ++k) {
        const float w = wp[(size_t)k * VOCAB];
        const float* s = sp + (size_t)k * BATCH;
        const float4 s0 = *(const float4*)(s);
        const float4 s1 = *(const float4*)(s + 4);
        const float4 s2 = *(const float4*)(s + 8);
        const float4 s3 = *(const float4*)(s + 12);
        acc[0]  = fmaf(s0.x, w, acc[0]);  acc[1]  = fmaf(s0.y, w, acc[1]);
        acc[2]  = fmaf(s0.z, w, acc[2]);  acc[3]  = fmaf(s0.w, w, acc[3]);
        acc[4]  = fmaf(s1.x, w, acc[4]);  acc[5]  = fmaf(s1.y, w, acc[5]);
        acc[6]  = fmaf(s1.z, w, acc[6]);  acc[7]  = fmaf(s1.w, w, acc[7]);
        acc[8]  = fmaf(s2.x, w, acc[8]);  acc[9]  = fmaf(s2.y, w, acc[9]);
        acc[10] = fmaf(s2.z, w, acc[10]); acc[11] = fmaf(s2.w, w, acc[11]);
        acc[12] = fmaf(s3.x, w, acc[12]); acc[13] = fmaf(s3.y, w, acc[13]);
        acc[14] = fmaf(s3.z, w, acc[14]); acc[15] = fmaf(s3.w, w, acc[15]);
    }
    const float fb = fc_b[col];
#pragma unroll
    for (int i = 0; i < 16; ++i)
        logits[(size_t)(b0 + i) * VOCAB + col] = acc[i] + fb;
}

extern "C" void kernel_launch(void* const* d_in, const int* in_sizes, int n_in,
                              void* d_out, int out_size, void* d_ws, size_t ws_size,
                              hipStream_t stream) {
    const int*   x      = (const int*)  d_in[0];
    const float* hidden = (const float*)d_in[1];
    const float* enc    = (const float*)d_in[2];
    const float* emb    = (const float*)d_in[3];
    const float* W1     = (const float*)d_in[4];
    const float* b1     = (const float*)d_in[5];
    const float* W2     = (const float*)d_in[6];
    const float* b2     = (const float*)d_in[7];
    const float* V      = (const float*)d_in[8];
    // d_in[9] = bV: softmax-invariant, unused. d_in[11] = gru_rk: multiplies h0==0, unused.
    const float* gru_k  = (const float*)d_in[10];
    const float* gru_b  = (const float*)d_in[12];
    const float* fc_W   = (const float*)d_in[13];
    const float* fc_b   = (const float*)d_in[14];

    float* out       = (float*)d_out;
    float* logits    = out;                          // 64*32000
    float* state_out = out + (size_t)BATCH * VOCAB;  // 64*1024
    float* attw      = state_out + (size_t)BATCH * UNITS;  // 64*128

    float* c      = (float*)d_ws;        // 65536 f
    float* score  = c + 65536;           // 8192 f
    float* gin    = score + 8192;        // 81920 f
    float* stateT = gin + 81920;         // 65536 f

    hipMemsetAsync(score, 0, (size_t)BATCH * TLEN * sizeof(float), stream);

    k_c      <<<dim3(16, 16), 256, 0, stream>>>(hidden, W2, b1, b2, c);
    k_score  <<<dim3(8, 64),  256, 0, stream>>>(enc, W1, c, V, score);
    k_softmax<<<64, 64, 0, stream>>>(score, attw);
    k_context<<<dim3(4, 64),  256, 0, stream>>>(enc, attw, gin);
    k_embed  <<<64, 256, 0, stream>>>(x, emb, gin);
    k_gru    <<<dim3(16, 16), 256, 0, stream>>>(gin, gru_k, gru_b, state_out, stateT);
    k_fc     <<<500, 256, 0, stream>>>(stateT, fc_W, fc_b, logits);
}

// Round 3
// 683.836 us; speedup vs baseline: 1.2418x; 1.2418x over previous
//
#include <hip/hip_runtime.h>
#include <math.h>

#define UNITS 1024
#define EMBD  256
#define BATCH 64
#define TLEN  128
#define VOCAB 32000
#define GIN_D (UNITS + EMBD)   // 1280

typedef short short8 __attribute__((ext_vector_type(8)));
typedef float f32x4  __attribute__((ext_vector_type(4)));

__device__ __forceinline__ unsigned short f2bf(float f) {
    unsigned int u = __float_as_uint(f);
    u += 0x7fffu + ((u >> 16) & 1u);   // RNE
    return (unsigned short)(u >> 16);
}
__device__ __forceinline__ unsigned int packbf(float lo, float hi) {
    return (unsigned int)f2bf(lo) | ((unsigned int)f2bf(hi) << 16);
}

// ---------------- K1: c[b,j] += hidden[b,k0:k0+256] @ W2[k0:,j]  (K-split 4) --------
__global__ __launch_bounds__(256) void k_c(const float* __restrict__ hidden,
                                           const float* __restrict__ W2,
                                           const float* __restrict__ b1,
                                           const float* __restrict__ b2,
                                           float* __restrict__ c) {
    const int lane = threadIdx.x & 63;
    const int j = blockIdx.x * 64 + lane;
    const int b = blockIdx.y * 4 + (threadIdx.x >> 6);
    const int k0 = blockIdx.z * 256;
    const float* hrow = hidden + (size_t)b * UNITS + k0;
    const float* wcol = W2 + (size_t)k0 * UNITS + j;
    float acc = 0.f;
#pragma unroll 8
    for (int k = 0; k < 256; ++k)
        acc = fmaf(hrow[k], wcol[(size_t)k * UNITS], acc);
    if (blockIdx.z == 0) acc += b1[j] + b2[j];
    atomicAdd(&c[(size_t)b * UNITS + j], acc);
}

// ---------------- K2: score via bf16 MFMA (unchanged from R2) -----------------------
__global__ __launch_bounds__(256, 2) void k_score(const float* __restrict__ enc,
                                                  const float* __restrict__ W1,
                                                  const float* __restrict__ c,
                                                  const float* __restrict__ V,
                                                  float* __restrict__ score) {
    __shared__ unsigned short As[128 * 72];
    __shared__ unsigned short Bs[128 * 72];
    const int jt   = blockIdx.x;         // 0..7
    const int b    = blockIdx.y;         // 0..63
    const int tid  = threadIdx.x;
    const int lane = tid & 63;
    const int wid  = tid >> 6;           // 0..3
    const int wr   = wid & 1;
    const int wc   = wid >> 1;
    const int quad = lane >> 4;
    const int l16  = lane & 15;

    const float* encb = enc + (size_t)b * TLEN * UNITS;
    const float* w1b  = W1 + jt * 128;

    f32x4 acc[4][4];
#pragma unroll
    for (int i = 0; i < 4; ++i)
#pragma unroll
        for (int j = 0; j < 4; ++j)
            acc[i][j] = (f32x4){0.f, 0.f, 0.f, 0.f};

    const int ar = tid >> 4;
    const int ac = tid & 15;
    const int bp = tid >> 5;
    const int bj = tid & 31;

    for (int kc = 0; kc < UNITS; kc += 64) {
        float4 av[8];
#pragma unroll
        for (int rr = 0; rr < 8; ++rr)
            av[rr] = *(const float4*)(encb + (size_t)(ar + rr * 16) * UNITS + kc + ac * 4);
        float4 bv0[4], bv1[4];
#pragma unroll
        for (int kk = 0; kk < 4; ++kk) {
            const int k0 = 2 * (bp + 8 * kk);
            bv0[kk] = *(const float4*)(w1b + (size_t)(kc + k0) * UNITS + bj * 4);
            bv1[kk] = *(const float4*)(w1b + (size_t)(kc + k0 + 1) * UNITS + bj * 4);
        }
        __syncthreads();
#pragma unroll
        for (int rr = 0; rr < 8; ++rr) {
            ushort4 h;
            h.x = f2bf(av[rr].x); h.y = f2bf(av[rr].y);
            h.z = f2bf(av[rr].z); h.w = f2bf(av[rr].w);
            *(ushort4*)&As[(ar + rr * 16) * 72 + ac * 4] = h;
        }
#pragma unroll
        for (int kk = 0; kk < 4; ++kk) {
            const int k0 = 2 * (bp + 8 * kk);
            *(unsigned int*)&Bs[(bj * 4 + 0) * 72 + k0] = packbf(bv0[kk].x, bv1[kk].x);
            *(unsigned int*)&Bs[(bj * 4 + 1) * 72 + k0] = packbf(bv0[kk].y, bv1[kk].y);
            *(unsigned int*)&Bs[(bj * 4 + 2) * 72 + k0] = packbf(bv0[kk].z, bv1[kk].z);
            *(unsigned int*)&Bs[(bj * 4 + 3) * 72 + k0] = packbf(bv0[kk].w, bv1[kk].w);
        }
        __syncthreads();
#pragma unroll
        for (int kk = 0; kk < 2; ++kk) {
            const int kb = kk * 32 + quad * 8;
            short8 af[4], bfr[4];
#pragma unroll
            for (int mt = 0; mt < 4; ++mt)
                af[mt] = *(const short8*)&As[(wr * 64 + mt * 16 + l16) * 72 + kb];
#pragma unroll
            for (int nt = 0; nt < 4; ++nt)
                bfr[nt] = *(const short8*)&Bs[(wc * 64 + nt * 16 + l16) * 72 + kb];
#pragma unroll
            for (int mt = 0; mt < 4; ++mt)
#pragma unroll
                for (int nt = 0; nt < 4; ++nt)
                    acc[mt][nt] = __builtin_amdgcn_mfma_f32_16x16x32_bf16(
                        af[mt], bfr[nt], acc[mt][nt], 0, 0, 0);
        }
    }

    float cv[4], vv[4];
#pragma unroll
    for (int nt = 0; nt < 4; ++nt) {
        const int col = wc * 64 + nt * 16 + l16;
        cv[nt] = c[(size_t)b * UNITS + jt * 128 + col];
        vv[nt] = V[jt * 128 + col];
    }
    float rs[16];
#pragma unroll
    for (int mt = 0; mt < 4; ++mt)
#pragma unroll
        for (int reg = 0; reg < 4; ++reg) {
            float s = 0.f;
#pragma unroll
            for (int nt = 0; nt < 4; ++nt)
                s += tanhf(acc[mt][nt][reg] + cv[nt]) * vv[nt];
            rs[mt * 4 + reg] = s;
        }
#pragma unroll
    for (int off = 1; off < 16; off <<= 1)
#pragma unroll
        for (int i = 0; i < 16; ++i)
            rs[i] += __shfl_xor(rs[i], off);
    if (l16 == 0) {
#pragma unroll
        for (int mt = 0; mt < 4; ++mt)
#pragma unroll
            for (int reg = 0; reg < 4; ++reg)
                atomicAdd(&score[b * TLEN + wr * 64 + mt * 16 + quad * 4 + reg],
                          rs[mt * 4 + reg]);
    }
}

// ---------------- K3: softmax over t ------------------------------------------------
__global__ void k_softmax(const float* __restrict__ score, float* __restrict__ attw) {
    const int b = blockIdx.x;
    const int lane = threadIdx.x;
    float s0 = score[b * TLEN + lane];
    float s1 = score[b * TLEN + 64 + lane];
    float m = fmaxf(s0, s1);
#pragma unroll
    for (int off = 1; off < 64; off <<= 1) m = fmaxf(m, __shfl_xor(m, off));
    const float e0 = expf(s0 - m);
    const float e1 = expf(s1 - m);
    float s = e0 + e1;
#pragma unroll
    for (int off = 1; off < 64; off <<= 1) s += __shfl_xor(s, off);
    const float inv = 1.f / s;
    attw[b * TLEN + lane] = e0 * inv;
    attw[b * TLEN + 64 + lane] = e1 * inv;
}

// ---------------- K4: context -> gin[:, :1024] --------------------------------------
__global__ __launch_bounds__(256) void k_context(const float* __restrict__ enc,
                                                 const float* __restrict__ attw,
                                                 float* __restrict__ gin) {
    const int b = blockIdx.y;
    const int k = blockIdx.x * 256 + threadIdx.x;
    __shared__ float w[TLEN];
    if (threadIdx.x < TLEN) w[threadIdx.x] = attw[b * TLEN + threadIdx.x];
    __syncthreads();
    const float* e = enc + (size_t)b * TLEN * UNITS + k;
    float acc = 0.f;
#pragma unroll 8
    for (int t = 0; t < TLEN; ++t)
        acc = fmaf(w[t], e[(size_t)t * UNITS], acc);
    gin[(size_t)b * GIN_D + k] = acc;
}

// ---------------- K5: embedding gather -> gin[:, 1024:1280] -------------------------
__global__ void k_embed(const int* __restrict__ x, const float* __restrict__ emb,
                        float* __restrict__ gin) {
    const int b = blockIdx.x;
    const int e = threadIdx.x;
    const int row = x[b];
    gin[(size_t)b * GIN_D + UNITS + e] = emb[(size_t)row * EMBD + e];
}

// ---------------- K6a: GRU gate accumulation (K-split 5, atomics) -------------------
// gz[b,i] += gin[b,k0:]@gru_k[k0:,i];  gh[b,i] += gin[b,k0:]@gru_k[k0:,2048+i]
__global__ __launch_bounds__(256) void k_gru_acc(const float* __restrict__ gin,
                                                 const float* __restrict__ gru_k,
                                                 const float* __restrict__ gru_b,
                                                 float* __restrict__ gz,
                                                 float* __restrict__ gh) {
    const int lane = threadIdx.x & 63;
    const int i = blockIdx.x * 64 + lane;
    const int b = blockIdx.y * 4 + (threadIdx.x >> 6);
    const int k0 = blockIdx.z * 256;
    const float* g = gin + (size_t)b * GIN_D + k0;
    const float* wz = gru_k + (size_t)k0 * 3072 + i;
    const float* wh = wz + 2048;
    float az = 0.f, ah = 0.f;
#pragma unroll 8
    for (int k = 0; k < 256; ++k) {
        const float gv = g[k];
        az = fmaf(gv, wz[(size_t)k * 3072], az);
        ah = fmaf(gv, wh[(size_t)k * 3072], ah);
    }
    if (blockIdx.z == 0) { az += gru_b[i]; ah += gru_b[2048 + i]; }
    atomicAdd(&gz[(size_t)b * UNITS + i], az);
    atomicAdd(&gh[(size_t)b * UNITS + i], ah);
}

// ---------------- K6b: GRU finalize -------------------------------------------------
__global__ __launch_bounds__(256) void k_gru_fin(const float* __restrict__ gz,
                                                 const float* __restrict__ gh,
                                                 float* __restrict__ state,
                                                 float* __restrict__ stateT) {
    const int lane = threadIdx.x & 63;
    const int i = blockIdx.x * 64 + lane;
    const int b = blockIdx.y * 4 + (threadIdx.x >> 6);
    const float az = gz[(size_t)b * UNITS + i];
    const float ah = gh[(size_t)b * UNITS + i];
    const float z = 1.f / (1.f + expf(-az));
    const float hh = tanhf(ah);
    const float st = (1.f - z) * hh;
    state[(size_t)b * UNITS + i] = st;
    stateT[(size_t)i * BATCH + b] = st;
}

// ---------------- K7: logits += stateT-slice @ fc_W-slice (K-split 8, atomics) ------
__global__ __launch_bounds__(256) void k_fc(const float* __restrict__ stateT,
                                            const float* __restrict__ fc_W,
                                            const float* __restrict__ fc_b,
                                            float* __restrict__ logits) {
    const int lane = threadIdx.x & 63;
    const int col = blockIdx.x * 64 + lane;
    const int b0 = (int)(threadIdx.x >> 6) * 16;
    const int k0 = blockIdx.y * 128;
    float acc[16];
#pragma unroll
    for (int i = 0; i < 16; ++i) acc[i] = 0.f;
    const float* wp = fc_W + (size_t)k0 * VOCAB + col;
    const float* sp = stateT + (size_t)k0 * BATCH + b0;
#pragma unroll 4
    for (int k = 0; k < 128; ++k) {
        const float w = wp[(size_t)k * VOCAB];
        const float* s = sp + (size_t)k * BATCH;
        const float4 s0 = *(const float4*)(s);
        const float4 s1 = *(const float4*)(s + 4);
        const float4 s2 = *(const float4*)(s + 8);
        const float4 s3 = *(const float4*)(s + 12);
        acc[0]  = fmaf(s0.x, w, acc[0]);  acc[1]  = fmaf(s0.y, w, acc[1]);
        acc[2]  = fmaf(s0.z, w, acc[2]);  acc[3]  = fmaf(s0.w, w, acc[3]);
        acc[4]  = fmaf(s1.x, w, acc[4]);  acc[5]  = fmaf(s1.y, w, acc[5]);
        acc[6]  = fmaf(s1.z, w, acc[6]);  acc[7]  = fmaf(s1.w, w, acc[7]);
        acc[8]  = fmaf(s2.x, w, acc[8]);  acc[9]  = fmaf(s2.y, w, acc[9]);
        acc[10] = fmaf(s2.z, w, acc[10]); acc[11] = fmaf(s2.w, w, acc[11]);
        acc[12] = fmaf(s3.x, w, acc[12]); acc[13] = fmaf(s3.y, w, acc[13]);
        acc[14] = fmaf(s3.z, w, acc[14]); acc[15] = fmaf(s3.w, w, acc[15]);
    }
    if (blockIdx.y == 0) {
        const float fb = fc_b[col];
#pragma unroll
        for (int i = 0; i < 16; ++i) acc[i] += fb;
    }
#pragma unroll
    for (int i = 0; i < 16; ++i)
        atomicAdd(&logits[(size_t)(b0 + i) * VOCAB + col], acc[i]);
}

extern "C" void kernel_launch(void* const* d_in, const int* in_sizes, int n_in,
                              void* d_out, int out_size, void* d_ws, size_t ws_size,
                              hipStream_t stream) {
    const int*   x      = (const int*)  d_in[0];
    const float* hidden = (const float*)d_in[1];
    const float* enc    = (const float*)d_in[2];
    const float* emb    = (const float*)d_in[3];
    const float* W1     = (const float*)d_in[4];
    const float* b1     = (const float*)d_in[5];
    const float* W2     = (const float*)d_in[6];
    const float* b2     = (const float*)d_in[7];
    const float* V      = (const float*)d_in[8];
    // d_in[9] = bV: softmax-invariant. d_in[11] = gru_rk: multiplies h0==0. Both unused.
    const float* gru_k  = (const float*)d_in[10];
    const float* gru_b  = (const float*)d_in[12];
    const float* fc_W   = (const float*)d_in[13];
    const float* fc_b   = (const float*)d_in[14];

    float* out       = (float*)d_out;
    float* logits    = out;                          // 64*32000
    float* state_out = out + (size_t)BATCH * VOCAB;  // 64*1024
    float* attw      = state_out + (size_t)BATCH * UNITS;  // 64*128

    float* c      = (float*)d_ws;        // 65536 f
    float* score  = c + 65536;           // 8192 f
    float* gin    = score + 8192;        // 81920 f
    float* stateT = gin + 81920;         // 65536 f
    float* gz     = stateT + 65536;      // 65536 f
    float* gh     = gz + 65536;          // 65536 f   (total ~1.41 MB)

    hipMemsetAsync(c, 0, (size_t)BATCH * UNITS * sizeof(float), stream);
    hipMemsetAsync(score, 0, (size_t)BATCH * TLEN * sizeof(float), stream);
    hipMemsetAsync(gz, 0, (size_t)2 * BATCH * UNITS * sizeof(float), stream);
    hipMemsetAsync(logits, 0, (size_t)BATCH * VOCAB * sizeof(float), stream);

    k_c      <<<dim3(16, 16, 4), 256, 0, stream>>>(hidden, W2, b1, b2, c);
    k_score  <<<dim3(8, 64),     256, 0, stream>>>(enc, W1, c, V, score);
    k_softmax<<<64, 64, 0, stream>>>(score, attw);
    k_context<<<dim3(4, 64),     256, 0, stream>>>(enc, attw, gin);
    k_embed  <<<64, 256, 0, stream>>>(x, emb, gin);
    k_gru_acc<<<dim3(16, 16, 5), 256, 0, stream>>>(gin, gru_k, gru_b, gz, gh);
    k_gru_fin<<<dim3(16, 16),    256, 0, stream>>>(gz, gh, state_out, stateT);
    k_fc     <<<dim3(500, 8),    256, 0, stream>>>(stateT, fc_W, fc_b, logits);
}